// Round 1
// 642.012 us; speedup vs baseline: 1.0106x; 1.0106x over previous
//
#include <hip/hip_runtime.h>

// Sinkhorn-Knopp, linear domain. One pass over P per iteration, NO atomics.
//   P = exp((mean+std*eps)/TAU) bf16 (f32-in-d_out fallback).
//   k_iter  (512 blk x 512 thr, 8 rows/blk, thread owns 8 cols):
//       v_j = rcp(csum_prev[j]);  u_i = rcp(sum_j P_ij v_j)  [block-local]
//       partial[b][j] = sum_{i in blk} u_i P_ij   -> coalesced 16 KB store
//   k_reduce (64 blk x 512 thr): csum_cur[j] = sum_b partial[b][j]
//   Sync = kernel launch boundary (R3: hand-rolled grid barrier ~70us - avoid;
//   R4: contended atomicAdd = 330ns/op/addr + 32B HBM write each - avoid).
//
// R5 (this round): kill stride-2 float4 wave patterns (lane i at byte 32i =>
//   every 64B line requested twice, half-used => request rate halves).
//   - k_init: 1 float4/thread, all loads/stores contiguous.
//   - partial/csum live in a PERMUTED column layout: thread t's low quad at
//     [4t], high quad at [2048+4t]. Pure internal permutation (k_reduce is
//     col-oblivious); k_iter P loads stay 16B; partial/csum fully coalesced.
//   - k_final: 1 float4/thread, csum read via inverse perm, stores contiguous.
//   Output bitwise-identical to R4 (same per-element arithmetic & order).

constexpr int N    = 4096;
constexpr int IT   = 30;
constexpr int NBLK = 512;           // iter blocks; 8 rows each
constexpr int TPB  = 512;

typedef __attribute__((ext_vector_type(8))) unsigned short ushort8v;
typedef __attribute__((ext_vector_type(4))) unsigned short ushort4v;

__device__ inline float bf2f(unsigned int h) {
    union { unsigned int u; float f; } x; x.u = h << 16; return x.f;
}
__device__ inline unsigned short f2bf(float f) {
    union { float f; unsigned int u; } x; x.f = f;
    unsigned int r = x.u + 0x7FFFu + ((x.u >> 16) & 1u);   // round-nearest-even
    return (unsigned short)(r >> 16);
}

struct V8 { float v[8]; };
struct V4 { float v[4]; };

template<typename PT>
__device__ inline V8 loadP8(const PT* base, int e);
template<> __device__ inline V8 loadP8<unsigned short>(const unsigned short* base, int e) {
    ushort8v p = *(const ushort8v*)(base + e);             // one dwordx4
    V8 r;
    #pragma unroll
    for (int k = 0; k < 8; ++k) r.v[k] = bf2f((unsigned int)p[k]);
    return r;
}
template<> __device__ inline V8 loadP8<float>(const float* base, int e) {
    float4 a = *(const float4*)(base + e);
    float4 b = *(const float4*)(base + e + 4);
    V8 r = {{a.x, a.y, a.z, a.w, b.x, b.y, b.z, b.w}};
    return r;
}

template<typename PT>
__device__ inline V4 loadP4(const PT* base, size_t e);
template<> __device__ inline V4 loadP4<unsigned short>(const unsigned short* base, size_t e) {
    ushort4v p = *(const ushort4v*)(base + e);             // one dwordx2
    V4 r;
    #pragma unroll
    for (int k = 0; k < 4; ++k) r.v[k] = bf2f((unsigned int)p[k]);
    return r;
}
template<> __device__ inline V4 loadP4<float>(const float* base, size_t e) {
    float4 a = *(const float4*)(base + e);
    V4 r = {{a.x, a.y, a.z, a.w}};
    return r;
}

// ---------------------------------------------------------------- init ------
// 1 float4 per thread: every wave access is 64 lanes x contiguous bytes.
template<typename PT>
__global__ __launch_bounds__(512) void k_init(const float* __restrict__ eps,
                                              const float* __restrict__ mean,
                                              const float* __restrict__ stdv,
                                              PT* __restrict__ P,
                                              float* __restrict__ bufA) {
    const int idx = blockIdx.x * 512 + threadIdx.x;        // float4 index, 0 .. N*N/4-1
    const float4 e = ((const float4*)eps )[(size_t)idx];
    const float4 m = ((const float4*)mean)[(size_t)idx];
    const float4 s = ((const float4*)stdv)[(size_t)idx];
    float p[4];
    p[0] = __expf((m.x + s.x * e.x) * 0.5f);
    p[1] = __expf((m.y + s.y * e.y) * 0.5f);
    p[2] = __expf((m.z + s.z * e.z) * 0.5f);
    p[3] = __expf((m.w + s.w * e.w) * 0.5f);
    if constexpr (sizeof(PT) == 2) {
        ushort4v o;
        #pragma unroll
        for (int k = 0; k < 4; ++k) o[k] = f2bf(p[k]);
        *(ushort4v*)((unsigned short*)P + 4 * (size_t)idx) = o;   // 8B contiguous
    } else {
        float4 a = {p[0], p[1], p[2], p[3]};
        ((float4*)P)[(size_t)idx] = a;
    }
    if (idx < N) bufA[idx] = 1.0f;     // csum_prev for iter 1: v = rcp(1) = 1
}

// ------------------------------------------------------- fused iteration ----
// Block b: rows [8b,8b+8). Thread t: actual cols [8t,8t+8).
// partial/csum use the PERMUTED layout: actual col 8t+j lives at
//   j<4 : 4t+j        (low half,  [0,2048))
//   j>=4: 2048+4t+j-4 (high half, [2048,4096))
// so every float4 access to partial/csum is wave-contiguous.
template<typename PT>
__global__ __launch_bounds__(TPB) void k_iter(const PT* __restrict__ P,
                                              const float* __restrict__ csum_prev,
                                              float* __restrict__ partial,
                                              float* __restrict__ u_glob) {
    __shared__ float ldsRow[8][8];   // [row][wave]
    __shared__ float ldsU[8];
    const int t    = threadIdx.x;
    const int wv   = t >> 6, lane = t & 63;
    const int b    = blockIdx.x;
    const int col0 = t * 8;          // actual cols (for P)
    const int q    = t * 4;          // permuted quad base (for partial/csum)
    const int row0 = b * 8;

    float4 c0 = *(const float4*)&csum_prev[q];
    float4 c1 = *(const float4*)&csum_prev[2048 + q];
    float v[8];
    v[0] = __builtin_amdgcn_rcpf(c0.x);  v[1] = __builtin_amdgcn_rcpf(c0.y);
    v[2] = __builtin_amdgcn_rcpf(c0.z);  v[3] = __builtin_amdgcn_rcpf(c0.w);
    v[4] = __builtin_amdgcn_rcpf(c1.x);  v[5] = __builtin_amdgcn_rcpf(c1.y);
    v[6] = __builtin_amdgcn_rcpf(c1.z);  v[7] = __builtin_amdgcn_rcpf(c1.w);

    V8 pf[8];
    #pragma unroll
    for (int i = 0; i < 8; ++i)
        pf[i] = loadP8(P + (size_t)(row0 + i) * N, col0);

    // row partials -> wave reduce -> LDS
    #pragma unroll
    for (int i = 0; i < 8; ++i) {
        float s = pf[i].v[0] * v[0] + pf[i].v[1] * v[1] + pf[i].v[2] * v[2] + pf[i].v[3] * v[3]
                + pf[i].v[4] * v[4] + pf[i].v[5] * v[5] + pf[i].v[6] * v[6] + pf[i].v[7] * v[7];
        #pragma unroll
        for (int off = 32; off; off >>= 1) s += __shfl_xor(s, off, 64);
        if (lane == 0) ldsRow[i][wv] = s;
    }
    __syncthreads();

    if (t < 64) {
        const int row = t >> 3, w = t & 7;
        float s = ldsRow[row][w];
        s += __shfl_xor(s, 1, 64);
        s += __shfl_xor(s, 2, 64);
        s += __shfl_xor(s, 4, 64);
        if (w == 0) {
            float u = __builtin_amdgcn_rcpf(s);
            ldsU[row] = u;
            u_glob[row0 + row] = u;          // last iteration's value used by k_final
        }
    }
    __syncthreads();

    // col contribution for this block's 8 rows; permuted coalesced store
    float acc[8] = {0, 0, 0, 0, 0, 0, 0, 0};
    #pragma unroll
    for (int i = 0; i < 8; ++i) {
        const float u = ldsU[i];
        #pragma unroll
        for (int k = 0; k < 8; ++k) acc[k] += u * pf[i].v[k];
    }
    float4 a  = {acc[0], acc[1], acc[2], acc[3]};
    float4 bb = {acc[4], acc[5], acc[6], acc[7]};
    *(float4*)&partial[(size_t)b * N + q]        = a;    // lanes: 1 KiB contiguous
    *(float4*)&partial[(size_t)b * N + 2048 + q] = bb;   // lanes: 1 KiB contiguous
}

// ----------------------------------------------------------- col reduce -----
// 64 blocks x 512 thr. Block owns 64 (permuted) cols; wave w sums chunk w.
// Column-oblivious: works identically on the permuted layout. UNCHANGED.
__global__ __launch_bounds__(512) void k_reduce(const float* __restrict__ partial,
                                                float* __restrict__ csum_cur) {
    __shared__ float red[8][64];
    const int t = threadIdx.x;
    const int lane = t & 63, wv = t >> 6;          // wv = chunk 0..7
    const int col = blockIdx.x * 64 + lane;
    float s = 0.0f;
    const float* p = partial + (size_t)(wv * 64) * N + col;
    #pragma unroll 8
    for (int b = 0; b < 64; ++b)
        s += p[(size_t)b * N];
    red[wv][lane] = s;
    __syncthreads();
    if (t < 64) {
        float acc = 0.0f;
        #pragma unroll
        for (int w = 0; w < 8; ++w) acc += red[w][t];
        csum_cur[blockIdx.x * 64 + t] = acc;
    }
}

// --------------------------------------------------------------- final ------
// 1 float4 per thread; csum read through the inverse permutation.
template<typename PT>
__global__ __launch_bounds__(256) void k_final(const PT* __restrict__ P,
                                               const float* __restrict__ u_glob,
                                               const float* __restrict__ csum_last,
                                               float* __restrict__ out) {
    const int idx = blockIdx.x * 256 + threadIdx.x;        // float4 index, 0 .. N*N/4-1
    const int row = idx >> 10;               // 1024 float4 per row
    const int c4  = (idx & 1023) * 4;        // actual col of this quad (mult of 4)
    const float u = u_glob[row];
    // actual quad c4 -> permuted position: (c4&4 ? 2048 : 0) + 4*(c4>>3)
    const int perm = ((c4 & 4) ? 2048 : 0) + ((c4 >> 3) << 2);
    float4 cc = *(const float4*)&csum_last[perm];
    V4 p = loadP4(P, (size_t)row * N + c4);
    float4 r;
    r.x = p.v[0] * u * __builtin_amdgcn_rcpf(cc.x);
    r.y = p.v[1] * u * __builtin_amdgcn_rcpf(cc.y);
    r.z = p.v[2] * u * __builtin_amdgcn_rcpf(cc.z);
    r.w = p.v[3] * u * __builtin_amdgcn_rcpf(cc.w);
    ((float4*)out)[(size_t)idx] = r;                       // lanes: 1 KiB contiguous
}

// ------------------------------------------------------------- launcher -----
extern "C" void kernel_launch(void* const* d_in, const int* in_sizes, int n_in,
                              void* d_out, int out_size, void* d_ws, size_t ws_size,
                              hipStream_t stream) {
    const float* eps  = (const float*)d_in[0];
    const float* mean = (const float*)d_in[1];
    const float* stdv = (const float*)d_in[2];
    float* out = (float*)d_out;
    char* ws = (char*)d_ws;

    // ws layout: [bufA bufB u_glob (64KB)] [partial 8MiB] [P bf16 32MiB]
    float* bufA   = (float*)ws;
    float* bufB   = bufA + N;
    float* u_glob = bufB + N;
    const size_t partOff = 64 * 1024;
    float* partial = (float*)(ws + partOff);
    const size_t partBytes = (size_t)NBLK * N * sizeof(float);     // 8 MiB
    const size_t pOff   = partOff + partBytes;
    const size_t pBytes = (size_t)N * N * sizeof(unsigned short);  // 32 MiB

    const int initGrid  = N * N / 4 / 512;    // 8192
    const int finalGrid = N * N / 4 / 256;    // 16384

    float* cs[2] = { bufA, bufB };

    if (ws_size >= pOff + pBytes) {
        unsigned short* P = (unsigned short*)(ws + pOff);
        k_init<unsigned short><<<initGrid, 512, 0, stream>>>(eps, mean, stdv, P, bufA);
        for (int t = 1; t <= IT; ++t) {
            k_iter<unsigned short><<<NBLK, TPB, 0, stream>>>(P, cs[(t - 1) & 1], partial, u_glob);
            k_reduce<<<64, 512, 0, stream>>>(partial, cs[t & 1]);
        }
        k_final<unsigned short><<<finalGrid, 256, 0, stream>>>(P, u_glob, cs[IT & 1], out);
    } else {
        float* P = out;                       // f32 fallback: P lives in d_out
        k_init<float><<<initGrid, 512, 0, stream>>>(eps, mean, stdv, P, bufA);
        for (int t = 1; t <= IT; ++t) {
            k_iter<float><<<NBLK, TPB, 0, stream>>>(P, cs[(t - 1) & 1], partial, u_glob);
            k_reduce<<<64, 512, 0, stream>>>(partial, cs[t & 1]);
        }
        k_final<float><<<finalGrid, 256, 0, stream>>>(P, u_glob, cs[IT & 1], out);
    }
}

// Round 2
// 586.174 us; speedup vs baseline: 1.1068x; 1.0953x over previous
//
#include <hip/hip_runtime.h>

// Sinkhorn-Knopp, linear domain. One pass over P per iteration, NO atomics.
//   P = exp((mean+std*eps)/TAU) bf16 (f32-in-d_out fallback).
//   k_first (256 blk x 512 thr): fused init + iteration 1 (v_j = 1):
//       compute P rows from inputs, store bf16, row sums -> u, col partials.
//   k_iter  (256 blk x 512 thr, 16 rows/blk, thread owns 8 cols, P kept as
//       PACKED bf16 in 64 VGPRs, unpacked twice - VALU is ~5% busy, free):
//       v_j = rcp(csum_prev[j]);  u_i = rcp(sum_j P_ij v_j)  [block-local]
//       partial[b][j] = sum_{i in blk} u_i P_ij   (4 MiB, was 8)
//   k_reduce (128 blk x 512 thr, was 64 blk = 1/4 of CUs): csum_cur[j].
//   Sync = kernel launch boundary (R3: hand-rolled grid barrier ~70us - avoid;
//   R4: contended atomicAdd = 330ns/op/addr + 32B HBM write each - avoid).
//
// R5 history: coalescing-only rewrite of k_init was a NO-OP (76us, 1.74TB/s,
//   VALUBusy 4.7% before AND after) => k_init is at a request-path plateau,
//   not a coalescing problem. 30 iterations = ~545us of the 642 total.
// R6 (this round): attack the iteration loop + delete k_init.
//   partial/csum keep the PERMUTED column layout: thread t's low quad at
//   [4t], high quad at [2048+4t] (pure internal permutation; k_reduce is
//   col-oblivious; k_final reads through the inverse perm).

constexpr int N    = 4096;
constexpr int IT   = 30;
constexpr int NBLK = 256;           // iter blocks; ROWS rows each
constexpr int ROWS = 16;
constexpr int TPB  = 512;

typedef __attribute__((ext_vector_type(8))) unsigned short ushort8v;

__device__ inline float bf2f(unsigned int h) {
    union { unsigned int u; float f; } x; x.u = h << 16; return x.f;
}
__device__ inline unsigned short f2bf(float f) {
    union { float f; unsigned int u; } x; x.f = f;
    unsigned int r = x.u + 0x7FFFu + ((x.u >> 16) & 1u);   // round-nearest-even
    return (unsigned short)(r >> 16);
}

struct V8 { float v[8]; };
struct V4 { float v[4]; };

// Packed in-register storage for one row-slice of 8 cols.
template<typename PT> struct StoreOf;
template<> struct StoreOf<unsigned short> { using T = ushort8v; };   // 4 VGPRs
template<> struct StoreOf<float>          { using T = V8;       };   // 8 VGPRs (fallback)

__device__ inline V8 unpackP(const ushort8v& s) {
    V8 r;
    #pragma unroll
    for (int k = 0; k < 8; ++k) r.v[k] = bf2f((unsigned int)s[k]);
    return r;
}
__device__ inline V8 unpackP(const V8& s) { return s; }

typedef __attribute__((ext_vector_type(4))) unsigned short ushort4v;
template<typename PT>
__device__ inline V4 loadP4(const PT* base, size_t e);
template<> __device__ inline V4 loadP4<unsigned short>(const unsigned short* base, size_t e) {
    ushort4v p = *(const ushort4v*)(base + e);             // one dwordx2
    V4 r;
    #pragma unroll
    for (int k = 0; k < 4; ++k) r.v[k] = bf2f((unsigned int)p[k]);
    return r;
}
template<> __device__ inline V4 loadP4<float>(const float* base, size_t e) {
    float4 a = *(const float4*)(base + e);
    V4 r = {{a.x, a.y, a.z, a.w}};
    return r;
}

// ----------------------------------------------- fused init + iteration 1 ---
// Block b: rows [16b,16b+16). Thread t: cols [8t,8t+8). v_j = 1 for iter 1.
template<typename PT>
__global__ __launch_bounds__(TPB) void k_first(const float* __restrict__ eps,
                                               const float* __restrict__ mean,
                                               const float* __restrict__ stdv,
                                               PT* __restrict__ P,
                                               float* __restrict__ partial,
                                               float* __restrict__ u_glob) {
    __shared__ float ldsRow[ROWS][8];
    __shared__ float ldsU[ROWS];
    const int t    = threadIdx.x;
    const int wv   = t >> 6, lane = t & 63;
    const int b    = blockIdx.x;
    const int col0 = t * 8;
    const int q    = t * 4;
    const int row0 = b * ROWS;

    typename StoreOf<PT>::T raw[ROWS];

    #pragma unroll
    for (int i = 0; i < ROWS; ++i) {
        const size_t rb = (size_t)(row0 + i) * N + col0;
        float4 e0 = *(const float4*)&eps [rb], e1 = *(const float4*)&eps [rb + 4];
        float4 m0 = *(const float4*)&mean[rb], m1 = *(const float4*)&mean[rb + 4];
        float4 s0 = *(const float4*)&stdv[rb], s1 = *(const float4*)&stdv[rb + 4];
        float p[8];
        p[0] = __expf((m0.x + s0.x * e0.x) * 0.5f);
        p[1] = __expf((m0.y + s0.y * e0.y) * 0.5f);
        p[2] = __expf((m0.z + s0.z * e0.z) * 0.5f);
        p[3] = __expf((m0.w + s0.w * e0.w) * 0.5f);
        p[4] = __expf((m1.x + s1.x * e1.x) * 0.5f);
        p[5] = __expf((m1.y + s1.y * e1.y) * 0.5f);
        p[6] = __expf((m1.z + s1.z * e1.z) * 0.5f);
        p[7] = __expf((m1.w + s1.w * e1.w) * 0.5f);
        if constexpr (sizeof(PT) == 2) {
            ushort8v o;
            #pragma unroll
            for (int k = 0; k < 8; ++k) o[k] = f2bf(p[k]);
            raw[i] = o;
            *(ushort8v*)((unsigned short*)P + rb) = o;     // 16B contiguous/lane
        } else {
            V8 r = {{p[0], p[1], p[2], p[3], p[4], p[5], p[6], p[7]}};
            raw[i] = r;
            float4 a = {p[0], p[1], p[2], p[3]}, bb = {p[4], p[5], p[6], p[7]};
            *(float4*)((float*)P + rb)     = a;
            *(float4*)((float*)P + rb + 4) = bb;
        }
    }

    // row sums (from the ROUNDED values, matching what later iters will read)
    #pragma unroll
    for (int i = 0; i < ROWS; ++i) {
        V8 pf = unpackP(raw[i]);
        float s = pf.v[0] + pf.v[1] + pf.v[2] + pf.v[3]
                + pf.v[4] + pf.v[5] + pf.v[6] + pf.v[7];
        #pragma unroll
        for (int off = 32; off; off >>= 1) s += __shfl_xor(s, off, 64);
        if (lane == 0) ldsRow[i][wv] = s;
    }
    __syncthreads();

    if (t < 8 * ROWS) {                       // 128 threads: 16 rows x 8 waves
        const int row = t >> 3, w = t & 7;
        float s = ldsRow[row][w];
        s += __shfl_xor(s, 1, 64);
        s += __shfl_xor(s, 2, 64);
        s += __shfl_xor(s, 4, 64);
        if (w == 0) {
            float u = __builtin_amdgcn_rcpf(s);
            ldsU[row] = u;
            u_glob[row0 + row] = u;
        }
    }
    __syncthreads();

    float acc[8] = {0, 0, 0, 0, 0, 0, 0, 0};
    #pragma unroll
    for (int i = 0; i < ROWS; ++i) {
        const float u = ldsU[i];
        V8 pf = unpackP(raw[i]);
        #pragma unroll
        for (int k = 0; k < 8; ++k) acc[k] += u * pf.v[k];
    }
    float4 a  = {acc[0], acc[1], acc[2], acc[3]};
    float4 bb = {acc[4], acc[5], acc[6], acc[7]};
    *(float4*)&partial[(size_t)b * N + q]        = a;
    *(float4*)&partial[(size_t)b * N + 2048 + q] = bb;
}

// ------------------------------------------------------- fused iteration ----
// Block b: rows [16b,16b+16). Thread t: actual cols [8t,8t+8).
template<typename PT>
__global__ __launch_bounds__(TPB) void k_iter(const PT* __restrict__ P,
                                              const float* __restrict__ csum_prev,
                                              float* __restrict__ partial,
                                              float* __restrict__ u_glob) {
    __shared__ float ldsRow[ROWS][8];
    __shared__ float ldsU[ROWS];
    const int t    = threadIdx.x;
    const int wv   = t >> 6, lane = t & 63;
    const int b    = blockIdx.x;
    const int col0 = t * 8;          // actual cols (for P)
    const int q    = t * 4;          // permuted quad base (for partial/csum)
    const int row0 = b * ROWS;

    float4 c0 = *(const float4*)&csum_prev[q];
    float4 c1 = *(const float4*)&csum_prev[2048 + q];
    float v[8];
    v[0] = __builtin_amdgcn_rcpf(c0.x);  v[1] = __builtin_amdgcn_rcpf(c0.y);
    v[2] = __builtin_amdgcn_rcpf(c0.z);  v[3] = __builtin_amdgcn_rcpf(c0.w);
    v[4] = __builtin_amdgcn_rcpf(c1.x);  v[5] = __builtin_amdgcn_rcpf(c1.y);
    v[6] = __builtin_amdgcn_rcpf(c1.z);  v[7] = __builtin_amdgcn_rcpf(c1.w);

    typename StoreOf<PT>::T raw[ROWS];
    #pragma unroll
    for (int i = 0; i < ROWS; ++i)
        raw[i] = *(const typename StoreOf<PT>::T*)(P + (size_t)(row0 + i) * N + col0);

    // row partials -> wave reduce -> LDS
    #pragma unroll
    for (int i = 0; i < ROWS; ++i) {
        V8 pf = unpackP(raw[i]);
        float s = pf.v[0] * v[0] + pf.v[1] * v[1] + pf.v[2] * v[2] + pf.v[3] * v[3]
                + pf.v[4] * v[4] + pf.v[5] * v[5] + pf.v[6] * v[6] + pf.v[7] * v[7];
        #pragma unroll
        for (int off = 32; off; off >>= 1) s += __shfl_xor(s, off, 64);
        if (lane == 0) ldsRow[i][wv] = s;
    }
    __syncthreads();

    if (t < 8 * ROWS) {                       // 128 threads: 16 rows x 8 waves
        const int row = t >> 3, w = t & 7;
        float s = ldsRow[row][w];
        s += __shfl_xor(s, 1, 64);
        s += __shfl_xor(s, 2, 64);
        s += __shfl_xor(s, 4, 64);
        if (w == 0) {
            float u = __builtin_amdgcn_rcpf(s);
            ldsU[row] = u;
            u_glob[row0 + row] = u;          // last iteration's value used by k_final
        }
    }
    __syncthreads();

    // col contribution for this block's 16 rows; permuted coalesced store
    float acc[8] = {0, 0, 0, 0, 0, 0, 0, 0};
    #pragma unroll
    for (int i = 0; i < ROWS; ++i) {
        const float u = ldsU[i];
        V8 pf = unpackP(raw[i]);
        #pragma unroll
        for (int k = 0; k < 8; ++k) acc[k] += u * pf.v[k];
    }
    float4 a  = {acc[0], acc[1], acc[2], acc[3]};
    float4 bb = {acc[4], acc[5], acc[6], acc[7]};
    *(float4*)&partial[(size_t)b * N + q]        = a;
    *(float4*)&partial[(size_t)b * N + 2048 + q] = bb;
}

// ----------------------------------------------------------- col reduce -----
// 128 blocks x 512 thr (was 64 blk = only 1/4 of CUs). Block owns 32
// (permuted) cols; 16 row-slices of 16 rows each. Column-oblivious.
__global__ __launch_bounds__(512) void k_reduce(const float* __restrict__ partial,
                                                float* __restrict__ csum_cur) {
    __shared__ float red[16][32];
    const int t = threadIdx.x;
    const int lane = t & 63, wv = t >> 6;              // 8 waves
    const int c     = blockIdx.x * 32 + (lane & 31);
    const int slice = wv * 2 + (lane >> 5);            // 0..15
    const float* p = partial + (size_t)(slice * 16) * N + c;
    float s = 0.0f;
    #pragma unroll 16
    for (int r = 0; r < 16; ++r)
        s += p[(size_t)r * N];
    red[slice][lane & 31] = s;
    __syncthreads();
    if (t < 32) {
        float acc = 0.0f;
        #pragma unroll
        for (int sl = 0; sl < 16; ++sl) acc += red[sl][t];
        csum_cur[blockIdx.x * 32 + t] = acc;
    }
}

// --------------------------------------------------------------- final ------
// 1 float4 per thread; csum read through the inverse permutation.
template<typename PT>
__global__ __launch_bounds__(256) void k_final(const PT* __restrict__ P,
                                               const float* __restrict__ u_glob,
                                               const float* __restrict__ csum_last,
                                               float* __restrict__ out) {
    const int idx = blockIdx.x * 256 + threadIdx.x;        // float4 index, 0 .. N*N/4-1
    const int row = idx >> 10;               // 1024 float4 per row
    const int c4  = (idx & 1023) * 4;        // actual col of this quad (mult of 4)
    const float u = u_glob[row];
    // actual quad c4 -> permuted position: (c4&4 ? 2048 : 0) + 4*(c4>>3)
    const int perm = ((c4 & 4) ? 2048 : 0) + ((c4 >> 3) << 2);
    float4 cc = *(const float4*)&csum_last[perm];
    V4 p = loadP4(P, (size_t)row * N + c4);
    float4 r;
    r.x = p.v[0] * u * __builtin_amdgcn_rcpf(cc.x);
    r.y = p.v[1] * u * __builtin_amdgcn_rcpf(cc.y);
    r.z = p.v[2] * u * __builtin_amdgcn_rcpf(cc.z);
    r.w = p.v[3] * u * __builtin_amdgcn_rcpf(cc.w);
    ((float4*)out)[(size_t)idx] = r;                       // lanes: 1 KiB contiguous
}

// ------------------------------------------------------------- launcher -----
extern "C" void kernel_launch(void* const* d_in, const int* in_sizes, int n_in,
                              void* d_out, int out_size, void* d_ws, size_t ws_size,
                              hipStream_t stream) {
    const float* eps  = (const float*)d_in[0];
    const float* mean = (const float*)d_in[1];
    const float* stdv = (const float*)d_in[2];
    float* out = (float*)d_out;
    char* ws = (char*)d_ws;

    // ws layout: [bufA bufB u_glob (64KB)] [partial 4MiB] [P bf16 32MiB]
    float* bufA   = (float*)ws;
    float* bufB   = bufA + N;
    float* u_glob = bufB + N;
    const size_t partOff = 64 * 1024;
    float* partial = (float*)(ws + partOff);
    const size_t partBytes = (size_t)NBLK * N * sizeof(float);     // 4 MiB
    const size_t pOff   = partOff + partBytes;
    const size_t pBytes = (size_t)N * N * sizeof(unsigned short);  // 32 MiB

    const int finalGrid = N * N / 4 / 256;    // 16384

    float* cs[2] = { bufA, bufB };

    if (ws_size >= pOff + pBytes) {
        unsigned short* P = (unsigned short*)(ws + pOff);
        k_first<unsigned short><<<NBLK, TPB, 0, stream>>>(eps, mean, stdv, P, partial, u_glob);
        k_reduce<<<128, 512, 0, stream>>>(partial, cs[1]);
        for (int t = 2; t <= IT; ++t) {
            k_iter<unsigned short><<<NBLK, TPB, 0, stream>>>(P, cs[(t - 1) & 1], partial, u_glob);
            k_reduce<<<128, 512, 0, stream>>>(partial, cs[t & 1]);
        }
        k_final<unsigned short><<<finalGrid, 256, 0, stream>>>(P, u_glob, cs[IT & 1], out);
    } else {
        float* P = out;                       // f32 fallback: P lives in d_out
        k_first<float><<<NBLK, TPB, 0, stream>>>(eps, mean, stdv, P, partial, u_glob);
        k_reduce<<<128, 512, 0, stream>>>(partial, cs[1]);
        for (int t = 2; t <= IT; ++t) {
            k_iter<float><<<NBLK, TPB, 0, stream>>>(P, cs[(t - 1) & 1], partial, u_glob);
            k_reduce<<<128, 512, 0, stream>>>(partial, cs[t & 1]);
        }
        k_final<float><<<finalGrid, 256, 0, stream>>>(P, u_glob, cs[IT & 1], out);
    }
}